// Round 4
// baseline (119.126 us; speedup 1.0000x reference)
//
#include <hip/hip_runtime.h>
#include <math.h>

#define H 2048
#define S 8192
#define NSL 128          // j-slices for u partials
#define KJ (H / NSL)     // 16 j-rows per slice

// u_part[js][k] = sum_{j in slice js} h[j] * W[j*H + k]
// float4 along k: 16B/lane streaming of W. grid (4, 128) = 512 blocks x 128 thr
// (2 blocks/CU), 16 independent float4 loads per thread for MLP. No atomics.
__global__ __launch_bounds__(128)
void wt_h_part(const float* __restrict__ W, const float* __restrict__ h,
               float* __restrict__ u_part) {
    const int k4 = blockIdx.x * 128 + threadIdx.x;     // float4 column (0..511)
    const int j0 = blockIdx.y * KJ;
    const float4* W4 = (const float4*)W;               // row j: W4[j*(H/4) + k4]
    float4 acc = make_float4(0.f, 0.f, 0.f, 0.f);
#pragma unroll
    for (int j = j0; j < j0 + KJ; ++j) {
        const float hv = h[j];
        const float4 w = W4[(size_t)j * (H / 4) + k4];
        acc.x += hv * w.x; acc.y += hv * w.y;
        acc.z += hv * w.z; acc.w += hv * w.w;
    }
    ((float4*)u_part)[(size_t)blockIdx.y * (H / 4) + k4] = acc;
}

// u[k] = sum_js u_part[js][k]  — 8 blocks x 256, 1 MB L2-hot.
__global__ __launch_bounds__(256)
void u_reduce(const float* __restrict__ u_part, float* __restrict__ u) {
    const int k = blockIdx.x * 256 + threadIdx.x;
    float acc = 0.f;
#pragma unroll 16
    for (int js = 0; js < NSL; ++js)
        acc += u_part[(size_t)js * H + k];
    u[k] = acc;
}

// e[s] = enc[s] . u — one wave per row, 4 rows/block, 2048 blocks.
// Tail: per-block softmax partials (m, sum(exp(e-m))) -> red[2b], red[2b+1].
__global__ __launch_bounds__(256)
void enc_dot_kernel(const float* __restrict__ enc, const float* __restrict__ u,
                    float* __restrict__ e, float* __restrict__ red) {
    __shared__ float ev[4];
    const int wave = threadIdx.x >> 6;
    const int lane = threadIdx.x & 63;
    const int s = blockIdx.x * 4 + wave;
    const float4* row = (const float4*)(enc + (size_t)s * H);
    const float4* u4  = (const float4*)u;
    float acc = 0.f;
#pragma unroll
    for (int it = 0; it < 8; ++it) {
        const float4 a = row[lane + 64 * it];
        const float4 b = u4 [lane + 64 * it];
        acc += a.x * b.x + a.y * b.y + a.z * b.z + a.w * b.w;
    }
#pragma unroll
    for (int off = 32; off > 0; off >>= 1) acc += __shfl_down(acc, off);
    if (lane == 0) { e[s] = acc; ev[wave] = acc; }
    __syncthreads();
    if (threadIdx.x == 0) {
        float m = fmaxf(fmaxf(ev[0], ev[1]), fmaxf(ev[2], ev[3]));
        float sb = 0.f;
#pragma unroll
        for (int i = 0; i < 4; ++i) sb += __expf(ev[i] - m);
        red[2 * blockIdx.x]     = m;
        red[2 * blockIdx.x + 1] = sb;
    }
}

// Each of 32 blocks redundantly reduces the 2048 (m,s) pairs (L2-hot),
// then writes its 256 outputs: out[i] = exp(e[i]-M) / Sum.
__global__ __launch_bounds__(256)
void finalize_kernel(const float* __restrict__ e, const float* __restrict__ red,
                     float* __restrict__ out) {
    __shared__ float wred[4];
    __shared__ float bc[2];
    const int tid = threadIdx.x;
    const int lane = tid & 63;
    const int wave = tid >> 6;
    const float2* pr = (const float2*)red;

    float m8[8], s8[8];
    float mt = -INFINITY;
#pragma unroll
    for (int q = 0; q < 8; ++q) {
        const float2 p = pr[tid + 256 * q];
        m8[q] = p.x; s8[q] = p.y;
        mt = fmaxf(mt, p.x);
    }
#pragma unroll
    for (int off = 32; off > 0; off >>= 1) mt = fmaxf(mt, __shfl_down(mt, off));
    if (lane == 0) wred[wave] = mt;
    __syncthreads();
    if (tid == 0) bc[0] = fmaxf(fmaxf(wred[0], wred[1]), fmaxf(wred[2], wred[3]));
    __syncthreads();
    const float M = bc[0];

    float st = 0.f;
#pragma unroll
    for (int q = 0; q < 8; ++q) st += s8[q] * __expf(m8[q] - M);
#pragma unroll
    for (int off = 32; off > 0; off >>= 1) st += __shfl_down(st, off);
    if (lane == 0) wred[wave] = st;
    __syncthreads();
    if (tid == 0) bc[1] = wred[0] + wred[1] + wred[2] + wred[3];
    __syncthreads();
    const float inv = 1.f / bc[1];

    const int i = blockIdx.x * 256 + tid;
    out[i] = __expf(e[i] - M) * inv;
}

extern "C" void kernel_launch(void* const* d_in, const int* in_sizes, int n_in,
                              void* d_out, int out_size, void* d_ws, size_t ws_size,
                              hipStream_t stream) {
    const float* hidden = (const float*)d_in[0];  // (1,1,H)
    const float* enc    = (const float*)d_in[1];  // (S,1,H)
    const float* W      = (const float*)d_in[2];  // (H,H)
    // d_in[3] = b: adds a constant to every energy -> softmax-invariant, ignored.
    float* out = (float*)d_out;                   // (1,1,S)

    float* u_part = (float*)d_ws;                 // NSL * H floats (1 MB)
    float* u      = u_part + (size_t)NSL * H;     // H floats
    float* e      = u + H;                        // S floats
    float* red    = e + S;                        // 2 * (S/4) floats

    wt_h_part<<<dim3(H / 4 / 128, NSL), 128, 0, stream>>>(W, hidden, u_part);

    u_reduce<<<H / 256, 256, 0, stream>>>(u_part, u);

    enc_dot_kernel<<<S / 4, 256, 0, stream>>>(enc, u, e, red);

    finalize_kernel<<<S / 256, 256, 0, stream>>>(e, red, out);
}

// Round 5
// 115.510 us; speedup vs baseline: 1.0313x; 1.0313x over previous
//
#include <hip/hip_runtime.h>
#include <math.h>

#define H 2048
#define S 8192
#define NSL 32   // j-slices for u partials
#define KJ (H / NSL)  // 64 j-rows per slice

// u_part[js][k] = sum_{j in slice js} h[j] * W[j*H + k]
// grid (H/256 = 8, NSL = 32), block 256. Coalesced along k, no atomics.
// NOTE (R4 post-mortem): float4/128-thr variant measured +4 us WORSE — this
// kernel is latency/launch-bound at ~3 us (2.7 us compulsory W traffic);
// scalar 256-thr is the empirically best shape.
__global__ __launch_bounds__(256)
void wt_h_part(const float* __restrict__ W, const float* __restrict__ h,
               float* __restrict__ u_part) {
    const int k  = blockIdx.x * 256 + threadIdx.x;
    const int j0 = blockIdx.y * KJ;
    float acc = 0.f;
#pragma unroll 8
    for (int j = j0; j < j0 + KJ; ++j)
        acc += h[j] * W[(size_t)j * H + k];
    u_part[(size_t)blockIdx.y * H + k] = acc;
}

// u[k] = sum_js u_part[js][k]  — 8 blocks x 256, 256 KB L2-hot.
__global__ __launch_bounds__(256)
void u_reduce(const float* __restrict__ u_part, float* __restrict__ u) {
    const int k = blockIdx.x * 256 + threadIdx.x;
    float acc = 0.f;
#pragma unroll
    for (int js = 0; js < NSL; ++js)
        acc += u_part[(size_t)js * H + k];
    u[k] = acc;
}

// e[s] = enc[s] . u — one wave per row, 4 rows/block, 2048 blocks (8/CU, max occ).
// BW-bound on enc (67.1 MB -> ~10.6 us floor). Tail: per-block softmax
// partials (m, sum(exp(e-m))) -> red[2b], red[2b+1].
__global__ __launch_bounds__(256)
void enc_dot_kernel(const float* __restrict__ enc, const float* __restrict__ u,
                    float* __restrict__ e, float* __restrict__ red) {
    __shared__ float ev[4];
    const int wave = threadIdx.x >> 6;
    const int lane = threadIdx.x & 63;
    const int s = blockIdx.x * 4 + wave;
    const float4* row = (const float4*)(enc + (size_t)s * H);
    const float4* u4  = (const float4*)u;
    float acc = 0.f;
#pragma unroll
    for (int it = 0; it < 8; ++it) {
        const float4 a = row[lane + 64 * it];
        const float4 b = u4 [lane + 64 * it];
        acc += a.x * b.x + a.y * b.y + a.z * b.z + a.w * b.w;
    }
#pragma unroll
    for (int off = 32; off > 0; off >>= 1) acc += __shfl_down(acc, off);
    if (lane == 0) { e[s] = acc; ev[wave] = acc; }
    __syncthreads();
    if (threadIdx.x == 0) {
        float m = fmaxf(fmaxf(ev[0], ev[1]), fmaxf(ev[2], ev[3]));
        float sb = 0.f;
#pragma unroll
        for (int i = 0; i < 4; ++i) sb += __expf(ev[i] - m);
        red[2 * blockIdx.x]     = m;
        red[2 * blockIdx.x + 1] = sb;
    }
}

// Each of 32 blocks redundantly reduces the 2048 (m,s) pairs (L2-hot),
// then writes its 256 outputs: out[i] = exp(e[i]-M) / Sum.
__global__ __launch_bounds__(256)
void finalize_kernel(const float* __restrict__ e, const float* __restrict__ red,
                     float* __restrict__ out) {
    __shared__ float wred[4];
    __shared__ float bc[2];
    const int tid = threadIdx.x;
    const int lane = tid & 63;
    const int wave = tid >> 6;
    const float2* pr = (const float2*)red;

    float m8[8], s8[8];
    float mt = -INFINITY;
#pragma unroll
    for (int q = 0; q < 8; ++q) {
        const float2 p = pr[tid + 256 * q];
        m8[q] = p.x; s8[q] = p.y;
        mt = fmaxf(mt, p.x);
    }
#pragma unroll
    for (int off = 32; off > 0; off >>= 1) mt = fmaxf(mt, __shfl_down(mt, off));
    if (lane == 0) wred[wave] = mt;
    __syncthreads();
    if (tid == 0) bc[0] = fmaxf(fmaxf(wred[0], wred[1]), fmaxf(wred[2], wred[3]));
    __syncthreads();
    const float M = bc[0];

    float st = 0.f;
#pragma unroll
    for (int q = 0; q < 8; ++q) st += s8[q] * __expf(m8[q] - M);
#pragma unroll
    for (int off = 32; off > 0; off >>= 1) st += __shfl_down(st, off);
    if (lane == 0) wred[wave] = st;
    __syncthreads();
    if (tid == 0) bc[1] = wred[0] + wred[1] + wred[2] + wred[3];
    __syncthreads();
    const float inv = 1.f / bc[1];

    const int i = blockIdx.x * 256 + tid;
    out[i] = __expf(e[i] - M) * inv;
}

extern "C" void kernel_launch(void* const* d_in, const int* in_sizes, int n_in,
                              void* d_out, int out_size, void* d_ws, size_t ws_size,
                              hipStream_t stream) {
    const float* hidden = (const float*)d_in[0];  // (1,1,H)
    const float* enc    = (const float*)d_in[1];  // (S,1,H)
    const float* W      = (const float*)d_in[2];  // (H,H)
    // d_in[3] = b: adds a constant to every energy -> softmax-invariant, ignored.
    float* out = (float*)d_out;                   // (1,1,S)

    float* u_part = (float*)d_ws;                 // NSL * H floats (256 KB)
    float* u      = u_part + (size_t)NSL * H;     // H floats
    float* e      = u + H;                        // S floats
    float* red    = e + S;                        // 2 * (S/4) floats

    wt_h_part<<<dim3(H / 256, NSL), 256, 0, stream>>>(W, hidden, u_part);

    u_reduce<<<H / 256, 256, 0, stream>>>(u_part, u);

    enc_dot_kernel<<<S / 4, 256, 0, stream>>>(enc, u, e, red);

    finalize_kernel<<<S / 256, 256, 0, stream>>>(e, red, out);
}